// Round 9
// baseline (121.546 us; speedup 1.0000x reference)
//
#include <hip/hip_runtime.h>

typedef _Float16 f16;
typedef f16 f16x8 __attribute__((ext_vector_type(8)));
typedef f16 f16x4 __attribute__((ext_vector_type(4)));
typedef float f32x4 __attribute__((ext_vector_type(4)));

// ---- per-WAVE LDS slice (units: f16), wave wid owns pixel rows {2wid, 2wid+1} ----
// x0: 5 rows x 24 cols, stride 28 (gy = ty*8-1  + 2wid + rr, rr in [0,5))
// x1: 8 rows x 44 cols, stride 48 (gy = ty*16-2 + 4wid + rr, rr in [0,8))
// x2 is NOT staged: layer-2 fragments are per-lane 2x16B contiguous global
// reads, L2-resident per-XCD (8 images x 256KB = 2MB < 4MB) via the swizzle.
// slice = 5*28 + 8*48 = 524 f16, padded to 544. 4 waves = 4.3 KB LDS.
#define X0OFF 0
#define X1OFF 140
#define WSL   544
#define LOG2E 1.4426950408889634f

// K' = 256 layout (8 ksteps of 32):
//  kp in [0,16)   : layer0, ki=kp>>2, kj=kp&3   ; real iff ki<3 && kj<3 -> orig = 3*ki+kj
//  kp in [16,64)  : layer1, kk=kp-16, ki=kk>>3, kj=kk&7 ; real iff kj<6 -> orig = 9+6*ki+kj
//  kp in [64,256) : layer2, kk=kp-64, ki=kk>>4, kj=kk&15; real iff kj<12 -> orig = 45+12*ki+kj
//
// Fragment-major storage: fragment f = (s*4 + t)*64 + lane holds the 8 f16
// W-elements (k = s*32 + quad*8 + j, n = t*16 + ln) -> every wave load is
// 64 lanes x 16 B CONTIGUOUS (1 KB).  Serves as the *A* operand
// (operand-swapped MFMA): A[m=ln][k=quad*8+j] = W[k][chan=t*16+ln].
__global__ void prep_wt(const float* __restrict__ W, f16* __restrict__ Wt) {
  const int f = blockIdx.x * 256 + threadIdx.x;   // 0..2047
  const int s = f >> 8;
  const int t = (f >> 6) & 3;
  const int lane = f & 63;
  const int quad = lane >> 4, ln = lane & 15;
  const int n = t * 16 + ln;
  f16 vals[8];
  #pragma unroll
  for (int j = 0; j < 8; ++j) {
    int kp = s * 32 + quad * 8 + j;
    int orig = -1;
    if (kp < 16)      { int ki = kp >> 2, kj = kp & 3;                   if (ki < 3 && kj < 3) orig = 3*ki + kj; }
    else if (kp < 64) { int kk = kp - 16; int ki = kk >> 3, kj = kk & 7;  if (kj < 6)          orig = 9 + 6*ki + kj; }
    else              { int kk = kp - 64; int ki = kk >> 4, kj = kk & 15; if (kj < 12)         orig = 45 + 12*ki + kj; }
    vals[j] = (f16)((orig >= 0) ? W[orig * 64 + n] : 0.f);
  }
  *(f16x8*)(Wt + (size_t)f * 8) = *(const f16x8*)vals;
}

// Operand-swapped MFMA: D = W_frag * patch_frag, D col = lane&15 = pixel-x,
// D row = 4*quad + r = channel-in-group.  chan = 16t + 4*quad + r.
// Wave-autonomous, barrier-free; x2 streamed global->MFMA (no staging head).
__global__ __launch_bounds__(256, 5) void fuse_kernel(
    const float* __restrict__ x0, const float* __restrict__ x1,
    const float* __restrict__ x2, const f16* __restrict__ Wt,
    float* __restrict__ out)
{
  __shared__ __align__(16) f16 tiles[4 * WSL];

  const int tid  = threadIdx.x;
  // bijective XCD swizzle: 2048 wgs = 8 XCDs x 256; XCD k owns images [8k, 8k+8)
  const int bid  = ((blockIdx.x & 7) << 8) | (blockIdx.x >> 3);
  const int nb   = bid >> 5;          // image
  const int ty8  = (bid >> 2) & 7;    // 8-px tile row
  const int tx   = bid & 3;           // 16-px tile col
  const int lane = tid & 63;
  const int wid  = tid >> 6;
  const int ln   = lane & 15;
  const int quad = lane >> 4;

  f16* sl = tiles + wid * WSL;        // this wave's private slice
  const f16* __restrict__ wfrag = Wt + (size_t)lane * 8;
  const float* __restrict__ img2 = x2 + nb * 65536;

  // ---- issue x1 (8 rows x 11 f32x4 = 88 = 64+24) and x0 (5x6=30) loads ----
  f32x4 v1a, v1b, v0;
  int w1a_off, w1b_off, w0_off;
  bool ok1b, ok0;
  {
    const float* img = x1 + nb * 16384;
    {
      int rr = lane / 11, c4 = lane - rr * 11;
      int gy = ty8 * 16 - 2 + 4 * wid + rr;
      int gx = tx * 32 - 4 + 4 * c4;
      bool inb = ((unsigned)gy < 128u) && ((unsigned)gx < 128u);
      v1a = inb ? *(const f32x4*)(img + gy * 128 + gx) : (f32x4){0.f, 0.f, 0.f, 0.f};
      w1a_off = X1OFF + rr * 48 + 4 * c4;
    }
    {
      int idx = lane + 64;
      int rr = idx / 11, c4 = idx - rr * 11;
      int gy = ty8 * 16 - 2 + 4 * wid + rr;
      int gx = tx * 32 - 4 + 4 * c4;
      ok1b = lane < 24;
      bool inb = ok1b && ((unsigned)gy < 128u) && ((unsigned)gx < 128u);
      v1b = inb ? *(const f32x4*)(img + gy * 128 + gx) : (f32x4){0.f, 0.f, 0.f, 0.f};
      w1b_off = X1OFF + rr * 48 + 4 * c4;
    }
  }
  {
    const float* img = x0 + nb * 4096;
    int rr = lane / 6, c4 = lane - rr * 6;
    int gy = ty8 * 8 - 1 + 2 * wid + rr;
    int gx = tx * 16 - 4 + 4 * c4;
    ok0 = lane < 30;
    bool inb = ok0 && ((unsigned)gy < 64u) && ((unsigned)gx < 64u);
    v0 = inb ? *(const f32x4*)(img + gy * 64 + gx) : (f32x4){0.f, 0.f, 0.f, 0.f};
    w0_off = X0OFF + rr * 28 + 4 * c4;
  }

  // x0 scale pixels for the epilogue (exact f32)
  float xs[2];
  #pragma unroll
  for (int cc = 0; cc < 2; ++cc)
    xs[cc] = x0[nb * 4096 + (ty8 * 8 + 2 * wid + cc) * 64 + tx * 16 + ln];

  // ---- per-lane x2 streaming constants ----
  // fragment: a[j] = x2[gy][gxlo+j], a[4+j] = x2[gy][gxlo+4+j]
  const int  gxlo   = tx * 64 - 8 + 4 * ln + 4 + 8 * (quad & 1);
  const bool oklo   = (unsigned)gxlo <= 252u;
  const bool okhi   = (unsigned)(gxlo + 4) <= 252u;
  const int  gxlo_c = gxlo < 0 ? 0 : (gxlo > 252 ? 252 : gxlo);
  const int  gxhi_c = (gxlo + 4) < 0 ? 0 : ((gxlo + 4) > 252 ? 252 : (gxlo + 4));
  const int  gy0    = ty8 * 32 - 4 + 8 * wid + (quad >> 1);  // + 4cc + 2(s-2)

  // ---- peel s=2: issue its x2 + bf loads BEFORE the LDS commits, so the
  // commit's vmcnt wait (on x1/x0, the oldest loads) overlaps their flight ----
  f32x4 lo2[2], hi2[2];
  bool  gyok2[2];
  #pragma unroll
  for (int cc = 0; cc < 2; ++cc) {
    int gy  = gy0 + 4 * cc;
    gyok2[cc] = (unsigned)gy < 256u;
    int gyc = gy < 0 ? 0 : (gy > 255 ? 255 : gy);
    const float* prow = img2 + gyc * 256;
    lo2[cc] = *(const f32x4*)(prow + gxlo_c);
    hi2[cc] = *(const f32x4*)(prow + gxhi_c);
  }
  f16x8 bf2[4];
  #pragma unroll
  for (int t = 0; t < 4; ++t)
    bf2[t] = *(const f16x8*)(wfrag + (8 + t) * 512);

  // ---- commit x1/x0 to this wave's slice ----
  {
    f16x4 h; h[0] = (f16)v1a[0]; h[1] = (f16)v1a[1]; h[2] = (f16)v1a[2]; h[3] = (f16)v1a[3];
    *(f16x4*)&sl[w1a_off] = h;
  }
  if (ok1b) {
    f16x4 h; h[0] = (f16)v1b[0]; h[1] = (f16)v1b[1]; h[2] = (f16)v1b[2]; h[3] = (f16)v1b[3];
    *(f16x4*)&sl[w1b_off] = h;
  }
  if (ok0) {
    f16x4 h; h[0] = (f16)v0[0]; h[1] = (f16)v0[1]; h[2] = (f16)v0[2]; h[3] = (f16)v0[3];
    *(f16x4*)&sl[w0_off] = h;
  }

  f32x4 acc[2][4];
  #pragma unroll
  for (int c = 0; c < 2; ++c)
    #pragma unroll
    for (int t = 0; t < 4; ++t)
      acc[c][t] = (f32x4){0.f, 0.f, 0.f, 0.f};

  // ---- s=2 compute ----
  #pragma unroll
  for (int cc = 0; cc < 2; ++cc) {
    f32x4 lo = (gyok2[cc] && oklo) ? lo2[cc] : (f32x4){0.f, 0.f, 0.f, 0.f};
    f32x4 hi = (gyok2[cc] && okhi) ? hi2[cc] : (f32x4){0.f, 0.f, 0.f, 0.f};
    f16x8 a;
    #pragma unroll
    for (int j = 0; j < 4; ++j) { a[j] = (f16)lo[j]; a[4 + j] = (f16)hi[j]; }
    #pragma unroll
    for (int t = 0; t < 4; ++t)
      acc[cc][t] = __builtin_amdgcn_mfma_f32_16x16x32_f16(bf2[t], a, acc[cc][t], 0, 0, 0);
  }

  // ---- ksteps 3..7: stream x2 from L2 + bf from Wt, pipelined by unroll ----
  #pragma unroll
  for (int s = 3; s < 8; ++s) {
    f16x8 bf[4];
    #pragma unroll
    for (int t = 0; t < 4; ++t)
      bf[t] = *(const f16x8*)(wfrag + (s * 4 + t) * 512);
    #pragma unroll
    for (int cc = 0; cc < 2; ++cc) {
      int gy  = gy0 + 4 * cc + 2 * (s - 2);
      bool gyok = (unsigned)gy < 256u;
      int gyc = gy < 0 ? 0 : (gy > 255 ? 255 : gy);
      const float* prow = img2 + gyc * 256;
      f32x4 lo = *(const f32x4*)(prow + gxlo_c);
      f32x4 hi = *(const f32x4*)(prow + gxhi_c);
      lo = (gyok && oklo) ? lo : (f32x4){0.f, 0.f, 0.f, 0.f};
      hi = (gyok && okhi) ? hi : (f32x4){0.f, 0.f, 0.f, 0.f};
      f16x8 a;
      #pragma unroll
      for (int j = 0; j < 4; ++j) { a[j] = (f16)lo[j]; a[4 + j] = (f16)hi[j]; }
      #pragma unroll
      for (int t = 0; t < 4; ++t)
        acc[cc][t] = __builtin_amdgcn_mfma_f32_16x16x32_f16(bf[t], a, acc[cc][t], 0, 0, 0);
    }
  }

  // ---- kstep 0 (LDS): quads 0,1 -> layer0 ; quads 2,3 -> layer1 ----
  {
    f16x8 bf[4];
    #pragma unroll
    for (int t = 0; t < 4; ++t)
      bf[t] = *(const f16x8*)(wfrag + t * 512);
    #pragma unroll
    for (int cc = 0; cc < 2; ++cc) {
      f16x8 a;
      if (quad < 2) {
        const int a0 = X0OFF + (cc + 2 * quad) * 28 + ln + 3;
        #pragma unroll
        for (int j = 0; j < 4; ++j) a[j]     = sl[a0 + j];
        #pragma unroll
        for (int j = 0; j < 4; ++j) a[4 + j] = sl[a0 + 28 + j];
      } else {
        const int a1 = X1OFF + (2 * cc + quad - 2) * 48 + 2 * ln + 2;
        #pragma unroll
        for (int j = 0; j < 8; ++j) a[j] = sl[a1 + j];
      }
      #pragma unroll
      for (int t = 0; t < 4; ++t)
        acc[cc][t] = __builtin_amdgcn_mfma_f32_16x16x32_f16(bf[t], a, acc[cc][t], 0, 0, 0);
    }
  }
  // ---- kstep 1 (LDS): all layer1, slice rr = 2cc + 2 + quad ----
  {
    f16x8 bf[4];
    #pragma unroll
    for (int t = 0; t < 4; ++t)
      bf[t] = *(const f16x8*)(wfrag + (4 + t) * 512);
    #pragma unroll
    for (int cc = 0; cc < 2; ++cc) {
      const int a1 = X1OFF + (2 * cc + 2 + quad) * 48 + 2 * ln + 2;
      f16x8 a;
      #pragma unroll
      for (int j = 0; j < 8; ++j) a[j] = sl[a1 + j];
      #pragma unroll
      for (int t = 0; t < 4; ++t)
        acc[cc][t] = __builtin_amdgcn_mfma_f32_16x16x32_f16(bf[t], a, acc[cc][t], 0, 0, 0);
    }
  }

  // ---- epilogue: fully in-register softmax + direct coalesced stores ----
  const int gx8 = (tx * 16 + ln) * 8;
  #pragma unroll
  for (int cc = 0; cc < 2; ++cc) {
    float v[4][4];
    float m = 0.f;                       // logits are post-ReLU, so >= 0
    #pragma unroll
    for (int t = 0; t < 4; ++t)
      #pragma unroll
      for (int r = 0; r < 4; ++r) {
        float x = fmaxf(acc[cc][t][r], 0.f);
        v[t][r] = x;
        m = fmaxf(m, x);
      }
    m = fmaxf(m, __shfl_xor(m, 16));
    m = fmaxf(m, __shfl_xor(m, 32));

    float sden = 0.f;
    #pragma unroll
    for (int t = 0; t < 4; ++t)
      #pragma unroll
      for (int r = 0; r < 4; ++r) {
        float e = exp2f((v[t][r] - m) * LOG2E);
        v[t][r] = e;
        sden += e;
      }
    sden += __shfl_xor(sden, 16);
    sden += __shfl_xor(sden, 32);

    // rcp (1-ulp) instead of precise divide: absmax is f16-quantization bound.
    const float sc = xs[cc] * __builtin_amdgcn_rcpf(sden);
    const int gy = ty8 * 8 + 2 * wid + cc;
    // chan = 16t + 4*quad + r -> addr = (gy*8 + 2t + (quad>>1))*512 + gx*8 + 4*(quad&1) + r
    float* op = out + nb * 262144 + (gy * 8 + (quad >> 1)) * 512 + gx8 + 4 * (quad & 1);
    #pragma unroll
    for (int t = 0; t < 4; ++t) {
      f32x4 w;
      w[0] = v[t][0] * sc; w[1] = v[t][1] * sc;
      w[2] = v[t][2] * sc; w[3] = v[t][3] * sc;
      *(f32x4*)(op + t * 1024) = w;      // regular store: through L2
    }
  }
}

extern "C" void kernel_launch(void* const* d_in, const int* in_sizes, int n_in,
                              void* d_out, int out_size, void* d_ws, size_t ws_size,
                              hipStream_t stream) {
  const float* x0 = (const float*)d_in[0];
  const float* x1 = (const float*)d_in[1];
  const float* x2 = (const float*)d_in[2];
  const float* W  = (const float*)d_in[3];
  float* outp     = (float*)d_out;
  f16* Wt         = (f16*)d_ws;   // 2048 fragments * 16 B = 32 KB

  prep_wt<<<dim3(8), dim3(256), 0, stream>>>(W, Wt);
  fuse_kernel<<<dim3(2048), dim3(256), 0, stream>>>(x0, x1, x2, Wt, outp);
}

// Round 10
// 110.738 us; speedup vs baseline: 1.0976x; 1.0976x over previous
//
#include <hip/hip_runtime.h>

typedef _Float16 f16;
typedef f16 f16x8 __attribute__((ext_vector_type(8)));
typedef f16 f16x4 __attribute__((ext_vector_type(4)));
typedef float f32x4 __attribute__((ext_vector_type(4)));

// ---- per-WAVE LDS slice (units: f16), wave wid owns pixel rows {2wid, 2wid+1} ----
// x0: 5 rows x 24 cols, stride 28 (gy = ty*8-1  + 2wid + rr, rr in [0,5))
// x1: 8 rows x 44 cols, stride 48 (gy = ty*16-2 + 4wid + rr, rr in [0,8))
// x2: 16 rows x 88 cols, stride 92 (gy = ty*32-4 + 8wid + rr, rr in [0,16))
// slice = 5*28 + 8*48 + 16*92 = 1996 f16, padded to 2048 (4 KB). 4 waves = 16 KB.
// NO cross-wave LDS sharing -> NO __syncthreads anywhere: each wave waits only
// on its own loads (compiler vmcnt/lgkmcnt).  Best measured config: 106.87 us.
#define X0OFF 0
#define X1OFF 140
#define X2OFF 524
#define WSL   2048
#define LOG2E 1.4426950408889634f

// K' = 256 layout (8 ksteps of 32):
//  kp in [0,16)   : layer0, ki=kp>>2, kj=kp&3   ; real iff ki<3 && kj<3 -> orig = 3*ki+kj
//  kp in [16,64)  : layer1, kk=kp-16, ki=kk>>3, kj=kk&7 ; real iff kj<6 -> orig = 9+6*ki+kj
//  kp in [64,256) : layer2, kk=kp-64, ki=kk>>4, kj=kk&15; real iff kj<12 -> orig = 45+12*ki+kj
//
// Fragment-major storage: fragment f = (s*4 + t)*64 + lane holds the 8 f16
// W-elements (k = s*32 + quad*8 + j, n = t*16 + ln) -> every wave load is
// 64 lanes x 16 B CONTIGUOUS (1 KB).  Serves as the *A* operand
// (operand-swapped MFMA): A[m=ln][k=quad*8+j] = W[k][chan=t*16+ln].
__global__ void prep_wt(const float* __restrict__ W, f16* __restrict__ Wt) {
  const int f = blockIdx.x * 256 + threadIdx.x;   // 0..2047
  const int s = f >> 8;
  const int t = (f >> 6) & 3;
  const int lane = f & 63;
  const int quad = lane >> 4, ln = lane & 15;
  const int n = t * 16 + ln;
  f16 vals[8];
  #pragma unroll
  for (int j = 0; j < 8; ++j) {
    int kp = s * 32 + quad * 8 + j;
    int orig = -1;
    if (kp < 16)      { int ki = kp >> 2, kj = kp & 3;                   if (ki < 3 && kj < 3) orig = 3*ki + kj; }
    else if (kp < 64) { int kk = kp - 16; int ki = kk >> 3, kj = kk & 7;  if (kj < 6)          orig = 9 + 6*ki + kj; }
    else              { int kk = kp - 64; int ki = kk >> 4, kj = kk & 15; if (kj < 12)         orig = 45 + 12*ki + kj; }
    vals[j] = (f16)((orig >= 0) ? W[orig * 64 + n] : 0.f);
  }
  *(f16x8*)(Wt + (size_t)f * 8) = *(const f16x8*)vals;
}

// Operand-swapped MFMA: D = W_frag * patch_frag, so D col = lane&15 = pixel-x,
// D row = 4*quad + r = channel-in-group.  chan = 16t + 4*quad + r.
// Softmax over 64 channels of one pixel = 16 in-lane values + shfl_xor(16,32).
// Wave-autonomous: zero barriers in the whole kernel.
__global__ __launch_bounds__(256, 6) void fuse_kernel(
    const float* __restrict__ x0, const float* __restrict__ x1,
    const float* __restrict__ x2, const f16* __restrict__ Wt,
    float* __restrict__ out)
{
  __shared__ __align__(16) f16 tiles[4 * WSL];

  const int tid  = threadIdx.x;
  // bijective XCD swizzle: 2048 wgs = 8 XCDs x 256; XCD k owns images [8k, 8k+8)
  const int bid  = ((blockIdx.x & 7) << 8) | (blockIdx.x >> 3);
  const int nb   = bid >> 5;          // image
  const int ty8  = (bid >> 2) & 7;    // 8-px tile row
  const int tx   = bid & 3;           // 16-px tile col
  const int lane = tid & 63;
  const int wid  = tid >> 6;
  const int ln   = lane & 15;
  const int quad = lane >> 4;

  f16* sl = tiles + wid * WSL;        // this wave's private slice
  const f16* __restrict__ wfrag = Wt + (size_t)lane * 8;

  // ---- issue x2 loads first (longest latency): 16 rows x 22 f32x4 = 352 = 5*64+32
  f32x4 v2[6];
  {
    const float* img = x2 + nb * 65536;
    #pragma unroll
    for (int i = 0; i < 6; ++i) {
      int idx = lane + 64 * i;
      int rr = idx / 22, c4 = idx - rr * 22;
      int gy = ty8 * 32 - 4 + 8 * wid + rr;
      int gx = tx * 64 - 8 + 4 * c4;
      bool inb = (i < 5 || lane < 32) && ((unsigned)gy < 256u) && ((unsigned)gx < 256u);
      v2[i] = inb ? *(const f32x4*)(img + gy * 256 + gx) : (f32x4){0.f, 0.f, 0.f, 0.f};
    }
  }

  // ---- stage x1 (8 rows x 11 f32x4 = 88 = 64+24) and x0 (5 x 6 = 30) ----
  {
    const float* img = x1 + nb * 16384;
    #pragma unroll
    for (int i = 0; i < 2; ++i) {
      int idx = lane + 64 * i;
      int rr = idx / 11, c4 = idx - rr * 11;
      int gy = ty8 * 16 - 2 + 4 * wid + rr;
      int gx = tx * 32 - 4 + 4 * c4;
      bool ok  = (i < 1 || lane < 24);
      bool inb = ok && ((unsigned)gy < 128u) && ((unsigned)gx < 128u);
      f32x4 t = inb ? *(const f32x4*)(img + gy * 128 + gx) : (f32x4){0.f, 0.f, 0.f, 0.f};
      if (ok) {
        f16x4 h; h[0] = (f16)t[0]; h[1] = (f16)t[1]; h[2] = (f16)t[2]; h[3] = (f16)t[3];
        *(f16x4*)&sl[X1OFF + rr * 48 + 4 * c4] = h;
      }
    }
  }
  {
    const float* img = x0 + nb * 4096;
    int rr = lane / 6, c4 = lane - rr * 6;
    int gy = ty8 * 8 - 1 + 2 * wid + rr;
    int gx = tx * 16 - 4 + 4 * c4;
    bool ok  = lane < 30;
    bool inb = ok && ((unsigned)gy < 64u) && ((unsigned)gx < 64u);
    f32x4 t = inb ? *(const f32x4*)(img + gy * 64 + gx) : (f32x4){0.f, 0.f, 0.f, 0.f};
    if (ok) {
      f16x4 h; h[0] = (f16)t[0]; h[1] = (f16)t[1]; h[2] = (f16)t[2]; h[3] = (f16)t[3];
      *(f16x4*)&sl[X0OFF + rr * 28 + 4 * c4] = h;
    }
  }

  // x0 scale pixels for the epilogue (exact f32); lane's pixel is (ty8*8+2wid+cc, tx*16+ln)
  float xs[2];
  #pragma unroll
  for (int cc = 0; cc < 2; ++cc)
    xs[cc] = x0[nb * 4096 + (ty8 * 8 + 2 * wid + cc) * 64 + tx * 16 + ln];

  // ---- commit x2 to this wave's slice (vmcnt deps handled by compiler) ----
  #pragma unroll
  for (int i = 0; i < 6; ++i) {
    if (i < 5 || lane < 32) {
      int idx = lane + 64 * i;
      int rr = idx / 22, c4 = idx - rr * 22;
      f16x4 h; h[0] = (f16)v2[i][0]; h[1] = (f16)v2[i][1];
      h[2] = (f16)v2[i][2]; h[3] = (f16)v2[i][3];
      *(f16x4*)&sl[X2OFF + rr * 92 + 4 * c4] = h;
    }
  }

  // kstep-0 weight fragments (independent of LDS; overlaps the lgkm drain)
  f16x8 bf0[4];
  #pragma unroll
  for (int t = 0; t < 4; ++t)
    bf0[t] = *(const f16x8*)(wfrag + t * 512);

  // NO barrier: wave reads only its own slice; compiler inserts lgkmcnt waits.

  f32x4 acc[2][4];
  #pragma unroll
  for (int c = 0; c < 2; ++c)
    #pragma unroll
    for (int t = 0; t < 4; ++t)
      acc[c][t] = (f32x4){0.f, 0.f, 0.f, 0.f};

  // ---- kstep 0: quads 0,1 -> layer0 ; quads 2,3 -> layer1 ----
  // slice rows: layer0 rr = cc + 2*quad (+1); layer1 rr = 2cc + quad - 2
  {
    #pragma unroll
    for (int cc = 0; cc < 2; ++cc) {
      f16x8 a;
      if (quad < 2) {
        const int a0 = X0OFF + (cc + 2 * quad) * 28 + ln + 3;
        #pragma unroll
        for (int j = 0; j < 4; ++j) a[j]     = sl[a0 + j];
        #pragma unroll
        for (int j = 0; j < 4; ++j) a[4 + j] = sl[a0 + 28 + j];
      } else {
        const int a1 = X1OFF + (2 * cc + quad - 2) * 48 + 2 * ln + 2;
        #pragma unroll
        for (int j = 0; j < 8; ++j) a[j] = sl[a1 + j];
      }
      #pragma unroll
      for (int t = 0; t < 4; ++t)
        acc[cc][t] = __builtin_amdgcn_mfma_f32_16x16x32_f16(bf0[t], a, acc[cc][t], 0, 0, 0);
    }
  }
  // ---- kstep 1: all layer1, slice rr = 2cc + 2 + quad ----
  {
    f16x8 bf[4];
    #pragma unroll
    for (int t = 0; t < 4; ++t)
      bf[t] = *(const f16x8*)(wfrag + (4 + t) * 512);
    #pragma unroll
    for (int cc = 0; cc < 2; ++cc) {
      const int a1 = X1OFF + (2 * cc + 2 + quad) * 48 + 2 * ln + 2;
      f16x8 a;
      #pragma unroll
      for (int j = 0; j < 8; ++j) a[j] = sl[a1 + j];
      #pragma unroll
      for (int t = 0; t < 4; ++t)
        acc[cc][t] = __builtin_amdgcn_mfma_f32_16x16x32_f16(bf[t], a, acc[cc][t], 0, 0, 0);
    }
  }
  // ---- ksteps 2..7: layer2, slice rr = 4cc + 2(s-2) + (quad>>1) ----
  #pragma unroll 3
  for (int s = 2; s < 8; ++s) {
    f16x8 bf[4];
    #pragma unroll
    for (int t = 0; t < 4; ++t)
      bf[t] = *(const f16x8*)(wfrag + (s * 4 + t) * 512);
    #pragma unroll
    for (int cc = 0; cc < 2; ++cc) {
      const int b2 = X2OFF + (4 * cc + 2 * (s - 2) + (quad >> 1)) * 92 + 4 * ln + 4 + 8 * (quad & 1);
      f16x4 lo = *(const f16x4*)&sl[b2];
      f16x4 hi = *(const f16x4*)&sl[b2 + 4];
      f16x8 a;
      a[0] = lo[0]; a[1] = lo[1]; a[2] = lo[2]; a[3] = lo[3];
      a[4] = hi[0]; a[5] = hi[1]; a[6] = hi[2]; a[7] = hi[3];
      #pragma unroll
      for (int t = 0; t < 4; ++t)
        acc[cc][t] = __builtin_amdgcn_mfma_f32_16x16x32_f16(bf[t], a, acc[cc][t], 0, 0, 0);
    }
  }

  // ---- epilogue: fully in-register softmax + direct coalesced stores ----
  const int gx8 = (tx * 16 + ln) * 8;
  #pragma unroll
  for (int cc = 0; cc < 2; ++cc) {
    float v[4][4];
    float m = 0.f;                       // logits are post-ReLU, so >= 0
    #pragma unroll
    for (int t = 0; t < 4; ++t)
      #pragma unroll
      for (int r = 0; r < 4; ++r) {
        float x = fmaxf(acc[cc][t][r], 0.f);
        v[t][r] = x;
        m = fmaxf(m, x);
      }
    m = fmaxf(m, __shfl_xor(m, 16));
    m = fmaxf(m, __shfl_xor(m, 32));

    float sden = 0.f;
    #pragma unroll
    for (int t = 0; t < 4; ++t)
      #pragma unroll
      for (int r = 0; r < 4; ++r) {
        float e = exp2f((v[t][r] - m) * LOG2E);
        v[t][r] = e;
        sden += e;
      }
    sden += __shfl_xor(sden, 16);
    sden += __shfl_xor(sden, 32);

    // rcp (1-ulp) instead of precise divide: absmax is f16-quantization bound.
    const float sc = xs[cc] * __builtin_amdgcn_rcpf(sden);
    const int gy = ty8 * 8 + 2 * wid + cc;
    // chan = 16t + 4*quad + r -> addr = (gy*8 + 2t + (quad>>1))*512 + gx*8 + 4*(quad&1) + r
    float* op = out + nb * 262144 + (gy * 8 + (quad >> 1)) * 512 + gx8 + 4 * (quad & 1);
    #pragma unroll
    for (int t = 0; t < 4; ++t) {
      f32x4 w;
      w[0] = v[t][0] * sc; w[1] = v[t][1] * sc;
      w[2] = v[t][2] * sc; w[3] = v[t][3] * sc;
      *(f32x4*)(op + t * 1024) = w;      // regular store: through L2
    }
  }
}

extern "C" void kernel_launch(void* const* d_in, const int* in_sizes, int n_in,
                              void* d_out, int out_size, void* d_ws, size_t ws_size,
                              hipStream_t stream) {
  const float* x0 = (const float*)d_in[0];
  const float* x1 = (const float*)d_in[1];
  const float* x2 = (const float*)d_in[2];
  const float* W  = (const float*)d_in[3];
  float* outp     = (float*)d_out;
  f16* Wt         = (f16*)d_ws;   // 2048 fragments * 16 B = 32 KB

  prep_wt<<<dim3(8), dim3(256), 0, stream>>>(W, Wt);
  fuse_kernel<<<dim3(2048), dim3(256), 0, stream>>>(x0, x1, x2, Wt, outp);
}